// Round 1
// baseline (756.341 us; speedup 1.0000x reference)
//
#include <hip/hip_runtime.h>
#include <hip/hip_bf16.h>

#define NTOK 2048
#define DIM 512
#define HID 2048
#define NEXP 64
#define NSLICE 8
#define HSLICE 256   // HID / NSLICE
#define TT 64        // token tile per pass
#define LN_EPS 1e-5f

// LDS layout (bytes):
//   [0, 20480)         Ws0 : weight stage buf 0, 256 cols x 40 bf16 (80 B/row)
//   [20480, 40960)     Ws1 : weight stage buf 1 (double buffer)
//   [40960, 73728)     Hs  : 64 tok x 256 h bf16, row 512B, xor-swizzled 16B chunks
// 73728 B/block -> exactly 2 blocks/CU (matches grid 512 / 256 CU)
#define WS0_OFF 0
#define WS1_OFF 20480
#define HS_OFF  40960
#define SMEM_BYTES 73728

typedef __bf16 bf16x8 __attribute__((ext_vector_type(8)));
typedef float f32x4 __attribute__((ext_vector_type(4)));

// Raw barrier with lgkmcnt(0) ONLY: LDS writes visible, but prefetch global
// loads stay in flight across the barrier (no vmcnt drain — the whole point).
#define LGKM_BARRIER() do { \
    asm volatile("s_waitcnt lgkmcnt(0)" ::: "memory"); \
    __builtin_amdgcn_s_barrier(); \
    asm volatile("" ::: "memory"); \
} while (0)

// ---------------- init: zero accumulator + counts ----------------
__global__ void init_kernel(float4* __restrict__ accb, int* __restrict__ counts) {
    int i = blockIdx.x * blockDim.x + threadIdx.x;
    accb[i] = make_float4(0.f, 0.f, 0.f, 0.f);
    if (i < NEXP) counts[i] = 0;
}

// ---------------- gating: softmax + top2 + bucket ----------------
__global__ void gate_kernel(const float* __restrict__ x,
                            const float* __restrict__ Wg,
                            const float* __restrict__ bg,
                            int* __restrict__ counts,
                            int* __restrict__ btok,
                            float* __restrict__ bw) {
    const int t = blockIdx.x;
    const int lane = threadIdx.x;  // 64 threads = 1 wave
    __shared__ float xs[DIM];
    const float4* xrow = (const float4*)(x + (size_t)t * DIM);
    ((float4*)xs)[lane] = xrow[lane];
    ((float4*)xs)[lane + 64] = xrow[lane + 64];
    __syncthreads();

    float acc = bg[lane];
    #pragma unroll 8
    for (int d = 0; d < DIM; d++) acc += xs[d] * Wg[d * NEXP + lane];

    float m = acc;
    #pragma unroll
    for (int off = 32; off; off >>= 1) m = fmaxf(m, __shfl_xor(m, off));
    float p = __expf(acc - m);
    float ssum = p;
    #pragma unroll
    for (int off = 32; off; off >>= 1) ssum += __shfl_xor(ssum, off);
    float prob = p / ssum;

    float v1 = prob; int i1 = lane;
    #pragma unroll
    for (int off = 32; off; off >>= 1) {
        float ov = __shfl_xor(v1, off);
        int   oi = __shfl_xor(i1, off);
        if (ov > v1 || (ov == v1 && oi < i1)) { v1 = ov; i1 = oi; }
    }
    float v2 = (lane == i1) ? -1e30f : prob; int i2 = lane;
    #pragma unroll
    for (int off = 32; off; off >>= 1) {
        float ov = __shfl_xor(v2, off);
        int   oi = __shfl_xor(i2, off);
        if (ov > v2 || (ov == v2 && oi < i2)) { v2 = ov; i2 = oi; }
    }

    if (lane == 0) {
        int s0 = atomicAdd(&counts[i1], 1);
        btok[i1 * NTOK + s0] = t;  bw[i1 * NTOK + s0] = v1;
        int s1 = atomicAdd(&counts[i2], 1);
        btok[i2 * NTOK + s1] = t;  bw[i2 * NTOK + s1] = v2;
    }
}

// Ws element offset (bf16 units) for (col 0..255, kgroup 0..3).
// 80 B col stride; kg slot XOR-swizzled by (col>>3)&3 so the staging writes
// (lanes own 4 consecutive cols -> 320 B lane stride) spread all 32 banks.
// Reads permute kg per col identically -> same conflict-free spread as before.
__device__ __forceinline__ int ws_off(int col, int kg) {
    return col * 40 + ((kg ^ ((col >> 3) & 3)) << 3);
}

// Issue 8 x dwordx4: rows wid*8+u (u=0..7) of a 32-row tile, cols lane*4..+3.
__device__ __forceinline__ void wload(const float* __restrict__ src, size_t rs,
                                      int wid, int lane, float4 v[8]) {
    const float* p = src + (size_t)(wid * 8) * rs + lane * 4;
    #pragma unroll
    for (int u = 0; u < 8; u++) v[u] = *(const float4*)(p + (size_t)u * rs);
}

// Convert + write the 8x4 register patch into Ws (kgroup = wid).
__device__ __forceinline__ void wstore(__bf16* __restrict__ wsb,
                                       int wid, int lane, const float4 v[8]) {
    #pragma unroll
    for (int j = 0; j < 4; j++) {
        bf16x8 pk;
        #pragma unroll
        for (int u = 0; u < 8; u++) {
            const float* f = (const float*)&v[u];
            pk[u] = (__bf16)f[j];
        }
        *(bf16x8*)(wsb + ws_off(lane * 4 + j, wid)) = pk;
    }
}

// Issue A-fragment loads for K-step ks (8 fp32 per mt from x, L2-resident).
__device__ __forceinline__ void aload(const float* __restrict__ x,
                                      const int toks[4], int ks, int lq,
                                      float4 ar[4][2]) {
    #pragma unroll
    for (int mt = 0; mt < 4; mt++) {
        const float* xp = x + (size_t)toks[mt] * DIM + ks * 32 + lq * 8;
        ar[mt][0] = *(const float4*)xp;
        ar[mt][1] = *(const float4*)(xp + 4);
    }
}

__device__ __forceinline__ void acvt(const float4 ar[4][2], bf16x8 af[4]) {
    #pragma unroll
    for (int mt = 0; mt < 4; mt++) {
        bf16x8 v;
        const float* f0 = (const float*)&ar[mt][0];
        const float* f1 = (const float*)&ar[mt][1];
        #pragma unroll
        for (int j = 0; j < 4; j++) { v[j] = (__bf16)f0[j]; v[4 + j] = (__bf16)f1[j]; }
        af[mt] = v;
    }
}

// ---------------- grouped FFN: per (expert, H-slice) block ----------------
// Pipelined staging: LDS double-buffered W tiles + depth-1 register prefetch
// of both the W tile and the x A-fragments; one lgkm-only barrier per K-step.
__global__ __launch_bounds__(256, 2) void ffn_kernel(
    const float* __restrict__ x,
    const float* __restrict__ W1, const float* __restrict__ b1,
    const float* __restrict__ W2, const float* __restrict__ b2,
    const int* __restrict__ counts,
    const int* __restrict__ btok, const float* __restrict__ bw,
    float* __restrict__ accb)
{
    __shared__ char smem[SMEM_BYTES];
    __bf16* ws0 = (__bf16*)(smem + WS0_OFF);
    __bf16* ws1 = (__bf16*)(smem + WS1_OFF);

    const int e = blockIdx.x >> 3;
    const int s = blockIdx.x & 7;
    const int n = counts[e];
    if (n <= 0) return;

    const int tid  = threadIdx.x;
    const int lane = tid & 63;
    const int wid  = tid >> 6;
    const int lq   = lane >> 4;                   // quad 0..3
    const int lm   = lane & 15;

    const float* W1s = W1 + (size_t)e * DIM * HID + s * HSLICE;        // row stride HID
    const float* W2s = W2 + ((size_t)e * HID + (size_t)s * HSLICE) * DIM; // row stride DIM
    const int*   btoke = btok + e * NTOK;
    const float* bwe   = bw   + e * NTOK;

    for (int t0 = 0; t0 < n; t0 += TT) {
        const int tiln = min(TT, n - t0);

        // per-lane A-row tokens (rows mt*16+lm); invalid rows fall back to a
        // valid token (finite garbage, rows are isolated in MFMA; epilogue guards)
        int toks[4];
        #pragma unroll
        for (int mt = 0; mt < 4; mt++) {
            int tr = mt * 16 + lm;
            toks[mt] = (tr < tiln) ? btoke[t0 + tr] : btoke[t0];
        }

        // ---- Phase A: h[64 x 256] = relu(X @ W1slice + b1) ----
        f32x4 acc[4][4];                          // [nt][mt]
        #pragma unroll
        for (int i = 0; i < 4; i++)
            #pragma unroll
            for (int j = 0; j < 4; j++) acc[i][j] = (f32x4)0.0f;

        float4 wv[8];
        float4 ar[4][2];

        // pipeline prologue: stage tile 0, put tile 1 + A(0) in flight
        wload(W1s, HID, wid, lane, wv);
        aload(x, toks, 0, lq, ar);
        wstore(ws0, wid, lane, wv);               // waits tile-0 loads only
        wload(W1s + (size_t)32 * HID, HID, wid, lane, wv);
        LGKM_BARRIER();
        int cur = 0;

        for (int ks = 0; ks < 16; ks++) {
            bf16x8 af[4];
            acvt(ar, af);                          // consume A(ks)
            if (ks < 15) aload(x, toks, ks + 1, lq, ar);   // A(ks+1) in flight

            const __bf16* wr = cur ? ws1 : ws0;
            #pragma unroll
            for (int nt = 0; nt < 4; nt++) {
                bf16x8 bfv = *(const bf16x8*)(wr + ws_off(wid * 64 + nt * 16 + lm, lq));
                #pragma unroll
                for (int mt = 0; mt < 4; mt++)
                    acc[nt][mt] = __builtin_amdgcn_mfma_f32_16x16x32_bf16(
                        af[mt], bfv, acc[nt][mt], 0, 0, 0);
            }
            if (ks < 15) {
                __bf16* ww = cur ? ws0 : ws1;
                wstore(ww, wid, lane, wv);         // consume W(ks+1)
                if (ks < 14)
                    wload(W1s + (size_t)((ks + 2) * 32) * HID, HID, wid, lane, wv);
                LGKM_BARRIER();
                cur ^= 1;
            }
        }

        // relu + b1 -> Hs (bf16, xor-swizzled). Hs is disjoint from Ws; the
        // last prior Hs readers are >15 barriers behind us.
        #pragma unroll
        for (int nt = 0; nt < 4; nt++) {
            int hloc0 = wid * 64 + nt * 16 + lm;
            float b1v = b1[e * HID + s * HSLICE + hloc0];
            #pragma unroll
            for (int mt = 0; mt < 4; mt++) {
                #pragma unroll
                for (int r = 0; r < 4; r++) {
                    int tr = mt * 16 + lq * 4 + r;
                    float v = fmaxf(acc[nt][mt][r] + b1v, 0.f);
                    *(__bf16*)(smem + HS_OFF + tr * 512 +
                               (((hloc0 >> 3) ^ (tr & 7)) * 16) + (hloc0 & 7) * 2) = (__bf16)v;
                }
            }
        }

        // ---- Phase B: Y[64 x 512] = Hs @ W2slice, atomic combine ----
        // Flattened 16 steps: u = dh*8 + kk; same pipeline structure.
        f32x4 yacc[4][4];
        wload(W2s, DIM, wid, lane, wv);            // u=0 (kk=0, dh=0)
        wstore(ws0, wid, lane, wv);                // last Phase-A reads were ws1
        wload(W2s + (size_t)32 * DIM, DIM, wid, lane, wv);  // u=1
        LGKM_BARRIER();                            // also publishes Hs writes
        cur = 0;

        for (int u = 0; u < 16; u++) {
            const int kk = u & 7, dh = u >> 3;
            if (kk == 0) {
                #pragma unroll
                for (int i = 0; i < 4; i++)
                    #pragma unroll
                    for (int j = 0; j < 4; j++) yacc[i][j] = (f32x4)0.0f;
            }

            bf16x8 af[4];
            const int kcA = kk * 4 + lq;
            #pragma unroll
            for (int mt = 0; mt < 4; mt++) {
                int tr = mt * 16 + lm;
                af[mt] = *(const bf16x8*)(smem + HS_OFF + tr * 512 + ((kcA ^ (tr & 7)) * 16));
            }
            const __bf16* wr = cur ? ws1 : ws0;
            #pragma unroll
            for (int nt = 0; nt < 4; nt++) {
                bf16x8 bfv = *(const bf16x8*)(wr + ws_off(wid * 64 + nt * 16 + lm, lq));
                #pragma unroll
                for (int mt = 0; mt < 4; mt++)
                    yacc[nt][mt] = __builtin_amdgcn_mfma_f32_16x16x32_bf16(
                        af[mt], bfv, yacc[nt][mt], 0, 0, 0);
            }
            if (u < 15) {
                __bf16* ww = cur ? ws0 : ws1;
                wstore(ww, wid, lane, wv);          // consume W(u+1)
                if (u < 14) {
                    const int un = u + 2;
                    wload(W2s + (size_t)((un & 7) * 32) * DIM + (un >> 3) * 256,
                          DIM, wid, lane, wv);
                }
                LGKM_BARRIER();
                cur ^= 1;
            }
            if (kk == 7) {
                // epilogue for this dh half: weighted atomic combine
                float b2s[4];
                #pragma unroll
                for (int nt = 0; nt < 4; nt++) {
                    int d = dh * 256 + wid * 64 + nt * 16 + lm;
                    b2s[nt] = (s == 0) ? b2[e * DIM + d] : 0.f;
                }
                #pragma unroll
                for (int mt = 0; mt < 4; mt++) {
                    #pragma unroll
                    for (int r = 0; r < 4; r++) {
                        int tr = mt * 16 + lq * 4 + r;
                        if (tr < tiln) {
                            int tok = btoke[t0 + tr];
                            float w = bwe[t0 + tr];
                            float* dst = accb + (size_t)tok * DIM;
                            #pragma unroll
                            for (int nt = 0; nt < 4; nt++) {
                                int d = dh * 256 + wid * 64 + nt * 16 + lm;
                                atomicAdd(dst + d, w * (yacc[nt][mt][r] + b2s[nt]));
                            }
                        }
                    }
                }
            }
        }
        // no trailing barrier needed: next tile's prologue writes ws0 (phase-B
        // step 15 read ws1) and its LGKM_BARRIER syncs before any ws0 read.
    }
}

// ---------------- residual + LayerNorm ----------------
__global__ void ln_kernel(const float* __restrict__ x,
                          const float* __restrict__ accb,
                          const float* __restrict__ gamma,
                          const float* __restrict__ beta,
                          float* __restrict__ out) {
    const int t = blockIdx.x;
    const int tid = threadIdx.x;                  // 256
    __shared__ float red[8];
    const size_t base = (size_t)t * DIM;
    float v0 = x[base + tid] + accb[base + tid];
    float v1 = x[base + 256 + tid] + accb[base + 256 + tid];
    float s  = v0 + v1;
    float sq = v0 * v0 + v1 * v1;
    #pragma unroll
    for (int off = 32; off; off >>= 1) { s += __shfl_xor(s, off); sq += __shfl_xor(sq, off); }
    if ((tid & 63) == 0) { red[tid >> 6] = s; red[4 + (tid >> 6)] = sq; }
    __syncthreads();
    float S  = red[0] + red[1] + red[2] + red[3];
    float SQ = red[4] + red[5] + red[6] + red[7];
    float mu  = S * (1.f / DIM);
    float var = SQ * (1.f / DIM) - mu * mu;
    float inv = rsqrtf(var + LN_EPS);
    out[base + tid]       = (v0 - mu) * inv * gamma[tid]       + beta[tid];
    out[base + 256 + tid] = (v1 - mu) * inv * gamma[256 + tid] + beta[256 + tid];
}

extern "C" void kernel_launch(void* const* d_in, const int* in_sizes, int n_in,
                              void* d_out, int out_size, void* d_ws, size_t ws_size,
                              hipStream_t stream) {
    const float* x     = (const float*)d_in[0];
    const float* Wg    = (const float*)d_in[1];
    const float* bg    = (const float*)d_in[2];
    const float* W1    = (const float*)d_in[3];
    const float* b1    = (const float*)d_in[4];
    const float* W2    = (const float*)d_in[5];
    const float* b2    = (const float*)d_in[6];
    const float* gamma = (const float*)d_in[7];
    const float* beta  = (const float*)d_in[8];

    char* ws = (char*)d_ws;
    int*   counts = (int*)ws;                                  // 256 B
    int*   btok   = (int*)(ws + 4096);                          // 512 KB
    float* bwv    = (float*)(ws + 4096 + 524288);               // 512 KB
    float* accb   = (float*)(ws + 4096 + 2 * 524288);           // 4 MB

    init_kernel<<<1024, 256, 0, stream>>>((float4*)accb, counts);
    gate_kernel<<<NTOK, 64, 0, stream>>>(x, Wg, bg, counts, btok, bwv);
    ffn_kernel<<<NEXP * NSLICE, 256, 0, stream>>>(x, W1, b1, W2, b2,
                                                  counts, btok, bwv, accb);
    ln_kernel<<<NTOK, 256, 0, stream>>>(x, accb, gamma, beta, (float*)d_out);
}

// Round 3
// 683.960 us; speedup vs baseline: 1.1058x; 1.1058x over previous
//
#include <hip/hip_runtime.h>
#include <hip/hip_bf16.h>

#define NTOK 2048
#define DIM 512
#define HID 2048
#define NEXP 64
#define NSLICE 16
#define HSLICE 128   // HID / NSLICE
#define TT 64        // token tile per pass
#define LN_EPS 1e-5f

// LDS layout (bytes), 26 KB/block -> 4 blocks/CU (with VGPR<=128 via
// __launch_bounds__(256,4)): occupancy is the lever this round.
//   [0, 10240)       Ws : 128 cols x 80 B  (32 k-values bf16 + 16B pad, kg-xor swizzled)
//   [10240, 26624)   Hs : 64 tok x 128 h bf16, row 256 B, xor-swizzled 16B chunks
#define WS_OFF 0
#define HS_OFF 10240
#define SMEM_BYTES 26624

typedef __bf16 bf16x8 __attribute__((ext_vector_type(8)));
typedef __bf16 bf16x4 __attribute__((ext_vector_type(4)));
typedef float f32x4 __attribute__((ext_vector_type(4)));

// ---------------- init: zero accumulator + counts ----------------
__global__ void init_kernel(float4* __restrict__ accb, int* __restrict__ counts) {
    int i = blockIdx.x * blockDim.x + threadIdx.x;
    accb[i] = make_float4(0.f, 0.f, 0.f, 0.f);
    if (i < NEXP) counts[i] = 0;
}

// ---------------- gating: softmax + top2 + bucket ----------------
__global__ void gate_kernel(const float* __restrict__ x,
                            const float* __restrict__ Wg,
                            const float* __restrict__ bg,
                            int* __restrict__ counts,
                            int* __restrict__ btok,
                            float* __restrict__ bw) {
    const int t = blockIdx.x;
    const int lane = threadIdx.x;  // 64 threads = 1 wave
    __shared__ float xs[DIM];
    const float4* xrow = (const float4*)(x + (size_t)t * DIM);
    ((float4*)xs)[lane] = xrow[lane];
    ((float4*)xs)[lane + 64] = xrow[lane + 64];
    __syncthreads();

    float acc = bg[lane];
    #pragma unroll 8
    for (int d = 0; d < DIM; d++) acc += xs[d] * Wg[d * NEXP + lane];

    float m = acc;
    #pragma unroll
    for (int off = 32; off; off >>= 1) m = fmaxf(m, __shfl_xor(m, off));
    float p = __expf(acc - m);
    float ssum = p;
    #pragma unroll
    for (int off = 32; off; off >>= 1) ssum += __shfl_xor(ssum, off);
    float prob = p / ssum;

    float v1 = prob; int i1 = lane;
    #pragma unroll
    for (int off = 32; off; off >>= 1) {
        float ov = __shfl_xor(v1, off);
        int   oi = __shfl_xor(i1, off);
        if (ov > v1 || (ov == v1 && oi < i1)) { v1 = ov; i1 = oi; }
    }
    float v2 = (lane == i1) ? -1e30f : prob; int i2 = lane;
    #pragma unroll
    for (int off = 32; off; off >>= 1) {
        float ov = __shfl_xor(v2, off);
        int   oi = __shfl_xor(i2, off);
        if (ov > v2 || (ov == v2 && oi < i2)) { v2 = ov; i2 = oi; }
    }

    if (lane == 0) {
        int s0 = atomicAdd(&counts[i1], 1);
        btok[i1 * NTOK + s0] = t;  bw[i1 * NTOK + s0] = v1;
        int s1 = atomicAdd(&counts[i2], 1);
        btok[i2 * NTOK + s1] = t;  bw[i2 * NTOK + s1] = v2;
    }
}

// Ws element offset (bf16 units) for (col 0..127, kgroup 0..3 of 8 k-values).
// 80 B col stride; kg slot XOR-swizzled by (col>>3)&3 -> conflict-free b128
// fragment reads (2-way max), mild 4-way on the b64 staging writes.
__device__ __forceinline__ int ws_off(int col, int kg) {
    return col * 40 + ((kg ^ ((col >> 3) & 3)) << 3);
}

// ---------------- grouped FFN: per (expert, H-slice) block ----------------
// 1024 blocks of 256 threads, 26KB LDS, VGPR<=128 -> 4 blocks/CU. Four
// independent blocks per CU hide each other's staging latency (the round-1
// in-block pipeline attempt was neutral + spilled; TLP is the lever).
__global__ __launch_bounds__(256, 4) void ffn_kernel(
    const float* __restrict__ x,
    const float* __restrict__ W1, const float* __restrict__ b1,
    const float* __restrict__ W2, const float* __restrict__ b2,
    const int* __restrict__ counts,
    const int* __restrict__ btok, const float* __restrict__ bw,
    float* __restrict__ accb)
{
    __shared__ char smem[SMEM_BYTES];
    __bf16* wsb = (__bf16*)(smem + WS_OFF);

    const int e = blockIdx.x >> 4;
    const int s = blockIdx.x & 15;
    const int n = counts[e];
    if (n <= 0) return;

    const int tid  = threadIdx.x;
    const int lane = tid & 63;
    const int wid  = tid >> 6;
    const int lq   = lane >> 4;                   // quad 0..3
    const int lm   = lane & 15;
    const int c0   = (tid & 31) * 4;              // staging: 4 cols
    const int r0   = (tid >> 5) * 4;              // staging: 4 k-rows

    const float* W1s = W1 + (size_t)e * DIM * HID + s * HSLICE;           // row stride HID
    const float* W2s = W2 + ((size_t)e * HID + (size_t)s * HSLICE) * DIM; // row stride DIM
    const int*   btoke = btok + e * NTOK;
    const float* bwe   = bw   + e * NTOK;

    for (int t0 = 0; t0 < n; t0 += TT) {
        const int tiln = min(TT, n - t0);

        // wave 'wid' owns tokens wid*16 .. wid*16+15 (A-row = lm within frag).
        // Invalid rows fall back to token 0 of the tile (finite garbage; rows
        // are independent in MFMA and the epilogue guards tr < tiln).
        const int tra = wid * 16 + lm;
        const int tok = btoke[t0 + (tra < tiln ? tra : 0)];
        const float* xrow = x + (size_t)tok * DIM;

        // ---- Phase A: h[16 tok x 128 h per wave] = relu(X @ W1slice + b1) ----
        f32x4 acc[8];
        #pragma unroll
        for (int i = 0; i < 8; i++) acc[i] = (f32x4)0.0f;

        for (int ks = 0; ks < 16; ks++) {          // K = 512, 32 per step
            // issue staging + A loads to registers BEFORE the barrier
            float4 wv[4];
            const float* wp = W1s + (size_t)(ks * 32 + r0) * HID + c0;
            #pragma unroll
            for (int u = 0; u < 4; u++) wv[u] = *(const float4*)(wp + (size_t)u * HID);
            float4 a0 = *(const float4*)(xrow + ks * 32 + lq * 8);
            float4 a1 = *(const float4*)(xrow + ks * 32 + lq * 8 + 4);

            __syncthreads();                        // prev readers of Ws done
            #pragma unroll
            for (int j = 0; j < 4; j++) {
                const float* f0 = (const float*)&wv[0];
                const float* f1 = (const float*)&wv[1];
                const float* f2 = (const float*)&wv[2];
                const float* f3 = (const float*)&wv[3];
                bf16x4 pk;
                pk[0] = (__bf16)f0[j]; pk[1] = (__bf16)f1[j];
                pk[2] = (__bf16)f2[j]; pk[3] = (__bf16)f3[j];
                *(bf16x4*)(wsb + ws_off(c0 + j, r0 >> 3) + (r0 & 7)) = pk;
            }
            bf16x8 af;
            {
                const float* f0 = (const float*)&a0;
                const float* f1 = (const float*)&a1;
                #pragma unroll
                for (int j = 0; j < 4; j++) { af[j] = (__bf16)f0[j]; af[4 + j] = (__bf16)f1[j]; }
            }
            __syncthreads();                        // Ws tile ready

            #pragma unroll
            for (int nt = 0; nt < 8; nt++) {
                bf16x8 bfv = *(const bf16x8*)(wsb + ws_off(nt * 16 + lm, lq));
                acc[nt] = __builtin_amdgcn_mfma_f32_16x16x32_bf16(af, bfv, acc[nt], 0, 0, 0);
            }
        }

        // relu + b1 -> Hs rows of THIS wave only (no cross-wave dependency)
        #pragma unroll
        for (int nt = 0; nt < 8; nt++) {
            int hloc = nt * 16 + lm;
            float b1v = b1[e * HID + s * HSLICE + hloc];
            #pragma unroll
            for (int r = 0; r < 4; r++) {
                int tr = wid * 16 + lq * 4 + r;
                float v = fmaxf(acc[nt][r] + b1v, 0.f);
                *(__bf16*)(smem + HS_OFF + tr * 256 +
                           (((hloc >> 3) ^ (tr & 7)) * 16) + (hloc & 7) * 2) = (__bf16)v;
            }
        }
        // no barrier needed: each wave reads back only its own Hs rows.

        // ---- Phase B: Y[16 tok x 512 d per wave] = Hs @ W2slice ----
        for (int dq = 0; dq < 4; dq++) {            // D = 512 in 4 quarters of 128
            f32x4 yacc[8];
            #pragma unroll
            for (int i = 0; i < 8; i++) yacc[i] = (f32x4)0.0f;

            for (int ks = 0; ks < 4; ks++) {        // K = 128 h in 4 steps of 32
                float4 wv[4];
                const float* wp = W2s + (size_t)(ks * 32 + r0) * DIM + dq * 128 + c0;
                #pragma unroll
                for (int u = 0; u < 4; u++) wv[u] = *(const float4*)(wp + (size_t)u * DIM);

                const int trb = wid * 16 + lm;
                bf16x8 af = *(const bf16x8*)(smem + HS_OFF + trb * 256 +
                                             (((ks * 4 + lq) ^ (trb & 7)) * 16));

                __syncthreads();                    // prev readers of Ws done
                #pragma unroll
                for (int j = 0; j < 4; j++) {
                    const float* f0 = (const float*)&wv[0];
                    const float* f1 = (const float*)&wv[1];
                    const float* f2 = (const float*)&wv[2];
                    const float* f3 = (const float*)&wv[3];
                    bf16x4 pk;
                    pk[0] = (__bf16)f0[j]; pk[1] = (__bf16)f1[j];
                    pk[2] = (__bf16)f2[j]; pk[3] = (__bf16)f3[j];
                    *(bf16x4*)(wsb + ws_off(c0 + j, r0 >> 3) + (r0 & 7)) = pk;
                }
                __syncthreads();                    // Ws tile ready

                #pragma unroll
                for (int nt = 0; nt < 8; nt++) {
                    bf16x8 bfv = *(const bf16x8*)(wsb + ws_off(nt * 16 + lm, lq));
                    yacc[nt] = __builtin_amdgcn_mfma_f32_16x16x32_bf16(af, bfv, yacc[nt], 0, 0, 0);
                }
            }

            // epilogue for this d-quarter: weighted atomic combine
            float b2s[8];
            #pragma unroll
            for (int nt = 0; nt < 8; nt++) {
                int d = dq * 128 + nt * 16 + lm;
                b2s[nt] = (s == 0) ? b2[e * DIM + d] : 0.f;
            }
            #pragma unroll
            for (int r = 0; r < 4; r++) {
                int tr = wid * 16 + lq * 4 + r;
                if (tr < tiln) {
                    int tok2 = btoke[t0 + tr];
                    float w = bwe[t0 + tr];
                    float* dst = accb + (size_t)tok2 * DIM;
                    #pragma unroll
                    for (int nt = 0; nt < 8; nt++) {
                        int d = dq * 128 + nt * 16 + lm;
                        atomicAdd(dst + d, w * (yacc[nt][r] + b2s[nt]));
                    }
                }
            }
        }
        __syncthreads();   // protect Hs/Ws before next tile
    }
}

// ---------------- residual + LayerNorm ----------------
__global__ void ln_kernel(const float* __restrict__ x,
                          const float* __restrict__ accb,
                          const float* __restrict__ gamma,
                          const float* __restrict__ beta,
                          float* __restrict__ out) {
    const int t = blockIdx.x;
    const int tid = threadIdx.x;                  // 256
    __shared__ float red[8];
    const size_t base = (size_t)t * DIM;
    float v0 = x[base + tid] + accb[base + tid];
    float v1 = x[base + 256 + tid] + accb[base + 256 + tid];
    float s  = v0 + v1;
    float sq = v0 * v0 + v1 * v1;
    #pragma unroll
    for (int off = 32; off; off >>= 1) { s += __shfl_xor(s, off); sq += __shfl_xor(sq, off); }
    if ((tid & 63) == 0) { red[tid >> 6] = s; red[4 + (tid >> 6)] = sq; }
    __syncthreads();
    float S  = red[0] + red[1] + red[2] + red[3];
    float SQ = red[4] + red[5] + red[6] + red[7];
    float mu  = S * (1.f / DIM);
    float var = SQ * (1.f / DIM) - mu * mu;
    float inv = rsqrtf(var + LN_EPS);
    out[base + tid]       = (v0 - mu) * inv * gamma[tid]       + beta[tid];
    out[base + 256 + tid] = (v1 - mu) * inv * gamma[256 + tid] + beta[256 + tid];
}

extern "C" void kernel_launch(void* const* d_in, const int* in_sizes, int n_in,
                              void* d_out, int out_size, void* d_ws, size_t ws_size,
                              hipStream_t stream) {
    const float* x     = (const float*)d_in[0];
    const float* Wg    = (const float*)d_in[1];
    const float* bg    = (const float*)d_in[2];
    const float* W1    = (const float*)d_in[3];
    const float* b1    = (const float*)d_in[4];
    const float* W2    = (const float*)d_in[5];
    const float* b2    = (const float*)d_in[6];
    const float* gamma = (const float*)d_in[7];
    const float* beta  = (const float*)d_in[8];

    char* ws = (char*)d_ws;
    int*   counts = (int*)ws;                                  // 256 B
    int*   btok   = (int*)(ws + 4096);                          // 512 KB
    float* bwv    = (float*)(ws + 4096 + 524288);               // 512 KB
    float* accb   = (float*)(ws + 4096 + 2 * 524288);           // 4 MB

    init_kernel<<<1024, 256, 0, stream>>>((float4*)accb, counts);
    gate_kernel<<<NTOK, 64, 0, stream>>>(x, Wg, bg, counts, btok, bwv);
    ffn_kernel<<<NEXP * NSLICE, 256, 0, stream>>>(x, W1, b1, W2, b2,
                                                  counts, btok, bwv, accb);
    ln_kernel<<<NTOK, 256, 0, stream>>>(x, accb, gamma, beta, (float*)d_out);
}

// Round 4
// 651.931 us; speedup vs baseline: 1.1602x; 1.0491x over previous
//
#include <hip/hip_runtime.h>
#include <hip/hip_bf16.h>

#define NTOK 2048
#define DIM 512
#define HID 2048
#define NEXP 64
#define NSLICE 16
#define HSLICE 128   // HID / NSLICE
#define TTM 128      // token capacity per weight pass (binomial max ~100 < 128)
#define LN_EPS 1e-5f

// LDS layout (bytes), 42 KB/block -> 3 blocks/CU (launch_bounds(256,3)).
//   [0, 10240)       Ws : 128 cols x 80 B (32 k bf16 + 16B pad, kg-xor swizzled)
//   [10240, 43008)   Hs : 128 tok x 128 h bf16, row 256 B, xor-swizzled 16B chunks
// One weight pass per block: every block does exactly 16+16 K-steps, no
// token-tile loop tail, weights fetched exactly once (round-3 lesson: the
// 2-tile blocks re-read 512KB and set the kernel's tail).
#define WS_OFF 0
#define HS_OFF 10240
#define SMEM_BYTES 43008

typedef __bf16 bf16x8 __attribute__((ext_vector_type(8)));
typedef __bf16 bf16x4 __attribute__((ext_vector_type(4)));
typedef float f32x4 __attribute__((ext_vector_type(4)));

// ---------------- init: zero accumulator + counts ----------------
__global__ void init_kernel(float4* __restrict__ accb, int* __restrict__ counts) {
    int i = blockIdx.x * blockDim.x + threadIdx.x;
    accb[i] = make_float4(0.f, 0.f, 0.f, 0.f);
    if (i < NEXP) counts[i] = 0;
}

// ---------------- gating: softmax + top2 + bucket ----------------
__global__ void gate_kernel(const float* __restrict__ x,
                            const float* __restrict__ Wg,
                            const float* __restrict__ bg,
                            int* __restrict__ counts,
                            int* __restrict__ btok,
                            float* __restrict__ bw) {
    const int t = blockIdx.x;
    const int lane = threadIdx.x;  // 64 threads = 1 wave
    __shared__ float xs[DIM];
    const float4* xrow = (const float4*)(x + (size_t)t * DIM);
    ((float4*)xs)[lane] = xrow[lane];
    ((float4*)xs)[lane + 64] = xrow[lane + 64];
    __syncthreads();

    float acc = bg[lane];
    #pragma unroll 8
    for (int d = 0; d < DIM; d++) acc += xs[d] * Wg[d * NEXP + lane];

    float m = acc;
    #pragma unroll
    for (int off = 32; off; off >>= 1) m = fmaxf(m, __shfl_xor(m, off));
    float p = __expf(acc - m);
    float ssum = p;
    #pragma unroll
    for (int off = 32; off; off >>= 1) ssum += __shfl_xor(ssum, off);
    float prob = p / ssum;

    float v1 = prob; int i1 = lane;
    #pragma unroll
    for (int off = 32; off; off >>= 1) {
        float ov = __shfl_xor(v1, off);
        int   oi = __shfl_xor(i1, off);
        if (ov > v1 || (ov == v1 && oi < i1)) { v1 = ov; i1 = oi; }
    }
    float v2 = (lane == i1) ? -1e30f : prob; int i2 = lane;
    #pragma unroll
    for (int off = 32; off; off >>= 1) {
        float ov = __shfl_xor(v2, off);
        int   oi = __shfl_xor(i2, off);
        if (ov > v2 || (ov == v2 && oi < i2)) { v2 = ov; i2 = oi; }
    }

    if (lane == 0) {
        int s0 = atomicAdd(&counts[i1], 1);
        btok[i1 * NTOK + s0] = t;  bw[i1 * NTOK + s0] = v1;
        int s1 = atomicAdd(&counts[i2], 1);
        btok[i2 * NTOK + s1] = t;  bw[i2 * NTOK + s1] = v2;
    }
}

// Ws element offset (bf16 units) for (col 0..127, kgroup 0..3 of 8 k-values).
__device__ __forceinline__ int ws_off(int col, int kg) {
    return col * 40 + ((kg ^ ((col >> 3) & 3)) << 3);
}

// ---------------- grouped FFN: per (expert, H-slice) block ----------------
__global__ __launch_bounds__(256, 3) void ffn_kernel(
    const float* __restrict__ x,
    const float* __restrict__ W1, const float* __restrict__ b1,
    const float* __restrict__ W2, const float* __restrict__ b2,
    const int* __restrict__ counts,
    const int* __restrict__ btok, const float* __restrict__ bw,
    float* __restrict__ accb)
{
    __shared__ char smem[SMEM_BYTES];
    __bf16* wsb = (__bf16*)(smem + WS_OFF);

    const int e = blockIdx.x >> 4;
    const int s = blockIdx.x & 15;
    const int n = counts[e];
    if (n <= 0) return;

    const int tid  = threadIdx.x;
    const int lane = tid & 63;
    const int wid  = tid >> 6;
    const int lq   = lane >> 4;                   // quad 0..3
    const int lm   = lane & 15;
    const int c0   = (tid & 31) * 4;              // staging: 4 cols
    const int r0   = (tid >> 5) * 4;              // staging: 4 k-rows

    const float* W1s = W1 + (size_t)e * DIM * HID + s * HSLICE;           // row stride HID
    const float* W2s = W2 + ((size_t)e * HID + (size_t)s * HSLICE) * DIM; // row stride DIM
    const int*   btoke = btok + e * NTOK;
    const float* bwe   = bw   + e * NTOK;

    for (int t0 = 0; t0 < n; t0 += TTM) {         // almost always 1 iteration
        const int tiln = min(TTM, n - t0);
        const bool two = (tiln > 64);             // block-uniform

        // wave 'wid' owns tokens g*64 + wid*16 + lm for groups g=0,1.
        const int tra0 = wid * 16 + lm;
        const int tok0 = btoke[t0 + (tra0 < tiln ? tra0 : 0)];
        const int tra1 = 64 + tra0;
        const int tok1 = two ? btoke[t0 + (tra1 < tiln ? tra1 : 0)] : tok0;
        const float* xrow0 = x + (size_t)tok0 * DIM;
        const float* xrow1 = x + (size_t)tok1 * DIM;

        // ---- Phase A: h[tiln x 128] = relu(X @ W1slice + b1) ----
        f32x4 acc0[8], acc1[8];
        #pragma unroll
        for (int i = 0; i < 8; i++) { acc0[i] = (f32x4)0.0f; acc1[i] = (f32x4)0.0f; }

        for (int ks = 0; ks < 16; ks++) {          // K = 512, 32 per step
            float4 wv[4];
            const float* wp = W1s + (size_t)(ks * 32 + r0) * HID + c0;
            #pragma unroll
            for (int u = 0; u < 4; u++) wv[u] = *(const float4*)(wp + (size_t)u * HID);
            float4 a00 = *(const float4*)(xrow0 + ks * 32 + lq * 8);
            float4 a01 = *(const float4*)(xrow0 + ks * 32 + lq * 8 + 4);
            float4 a10, a11;
            if (two) {
                a10 = *(const float4*)(xrow1 + ks * 32 + lq * 8);
                a11 = *(const float4*)(xrow1 + ks * 32 + lq * 8 + 4);
            }

            __syncthreads();                        // prev readers of Ws done
            #pragma unroll
            for (int j = 0; j < 4; j++) {
                const float* f0 = (const float*)&wv[0];
                const float* f1 = (const float*)&wv[1];
                const float* f2 = (const float*)&wv[2];
                const float* f3 = (const float*)&wv[3];
                bf16x4 pk;
                pk[0] = (__bf16)f0[j]; pk[1] = (__bf16)f1[j];
                pk[2] = (__bf16)f2[j]; pk[3] = (__bf16)f3[j];
                *(bf16x4*)(wsb + ws_off(c0 + j, r0 >> 3) + (r0 & 7)) = pk;
            }
            bf16x8 af0, af1;
            {
                const float* f0 = (const float*)&a00;
                const float* f1 = (const float*)&a01;
                #pragma unroll
                for (int j = 0; j < 4; j++) { af0[j] = (__bf16)f0[j]; af0[4 + j] = (__bf16)f1[j]; }
            }
            if (two) {
                const float* f0 = (const float*)&a10;
                const float* f1 = (const float*)&a11;
                #pragma unroll
                for (int j = 0; j < 4; j++) { af1[j] = (__bf16)f0[j]; af1[4 + j] = (__bf16)f1[j]; }
            }
            __syncthreads();                        // Ws tile ready

            #pragma unroll
            for (int nt = 0; nt < 8; nt++) {
                bf16x8 bfv = *(const bf16x8*)(wsb + ws_off(nt * 16 + lm, lq));
                acc0[nt] = __builtin_amdgcn_mfma_f32_16x16x32_bf16(af0, bfv, acc0[nt], 0, 0, 0);
                if (two)
                    acc1[nt] = __builtin_amdgcn_mfma_f32_16x16x32_bf16(af1, bfv, acc1[nt], 0, 0, 0);
            }
        }

        // relu + b1 -> Hs rows of THIS wave only (no cross-wave dependency)
        #pragma unroll
        for (int nt = 0; nt < 8; nt++) {
            int hloc = nt * 16 + lm;
            float b1v = b1[e * HID + s * HSLICE + hloc];
            #pragma unroll
            for (int r = 0; r < 4; r++) {
                int tr = wid * 16 + lq * 4 + r;
                float v = fmaxf(acc0[nt][r] + b1v, 0.f);
                *(__bf16*)(smem + HS_OFF + tr * 256 +
                           (((hloc >> 3) ^ (tr & 7)) * 16) + (hloc & 7) * 2) = (__bf16)v;
                if (two) {
                    int tr1 = 64 + tr;
                    float v1 = fmaxf(acc1[nt][r] + b1v, 0.f);
                    *(__bf16*)(smem + HS_OFF + tr1 * 256 +
                               (((hloc >> 3) ^ (tr1 & 7)) * 16) + (hloc & 7) * 2) = (__bf16)v1;
                }
            }
        }
        // no barrier needed: each wave reads back only its own Hs rows.

        // ---- Phase B: Y[tiln x 512] = Hs @ W2slice ----
        for (int dq = 0; dq < 4; dq++) {            // D = 512 in 4 quarters of 128
            f32x4 yacc0[8], yacc1[8];
            #pragma unroll
            for (int i = 0; i < 8; i++) { yacc0[i] = (f32x4)0.0f; yacc1[i] = (f32x4)0.0f; }

            for (int ks = 0; ks < 4; ks++) {        // K = 128 h in 4 steps of 32
                float4 wv[4];
                const float* wp = W2s + (size_t)(ks * 32 + r0) * DIM + dq * 128 + c0;
                #pragma unroll
                for (int u = 0; u < 4; u++) wv[u] = *(const float4*)(wp + (size_t)u * DIM);

                const int trb0 = wid * 16 + lm;
                bf16x8 af0 = *(const bf16x8*)(smem + HS_OFF + trb0 * 256 +
                                              (((ks * 4 + lq) ^ (trb0 & 7)) * 16));
                bf16x8 af1;
                if (two) {
                    const int trb1 = 64 + trb0;
                    af1 = *(const bf16x8*)(smem + HS_OFF + trb1 * 256 +
                                           (((ks * 4 + lq) ^ (trb1 & 7)) * 16));
                }

                __syncthreads();                    // prev readers of Ws done
                #pragma unroll
                for (int j = 0; j < 4; j++) {
                    const float* f0 = (const float*)&wv[0];
                    const float* f1 = (const float*)&wv[1];
                    const float* f2 = (const float*)&wv[2];
                    const float* f3 = (const float*)&wv[3];
                    bf16x4 pk;
                    pk[0] = (__bf16)f0[j]; pk[1] = (__bf16)f1[j];
                    pk[2] = (__bf16)f2[j]; pk[3] = (__bf16)f3[j];
                    *(bf16x4*)(wsb + ws_off(c0 + j, r0 >> 3) + (r0 & 7)) = pk;
                }
                __syncthreads();                    // Ws tile ready

                #pragma unroll
                for (int nt = 0; nt < 8; nt++) {
                    bf16x8 bfv = *(const bf16x8*)(wsb + ws_off(nt * 16 + lm, lq));
                    yacc0[nt] = __builtin_amdgcn_mfma_f32_16x16x32_bf16(af0, bfv, yacc0[nt], 0, 0, 0);
                    if (two)
                        yacc1[nt] = __builtin_amdgcn_mfma_f32_16x16x32_bf16(af1, bfv, yacc1[nt], 0, 0, 0);
                }
            }

            // epilogue for this d-quarter: weighted atomic combine
            float b2s[8];
            #pragma unroll
            for (int nt = 0; nt < 8; nt++) {
                int d = dq * 128 + nt * 16 + lm;
                b2s[nt] = (s == 0) ? b2[e * DIM + d] : 0.f;
            }
            #pragma unroll
            for (int r = 0; r < 4; r++) {
                int tr = wid * 16 + lq * 4 + r;
                if (tr < tiln) {
                    int tok2 = btoke[t0 + tr];
                    float w = bwe[t0 + tr];
                    float* dst = accb + (size_t)tok2 * DIM;
                    #pragma unroll
                    for (int nt = 0; nt < 8; nt++) {
                        int d = dq * 128 + nt * 16 + lm;
                        atomicAdd(dst + d, w * (yacc0[nt][r] + b2s[nt]));
                    }
                }
                if (two) {
                    int tr1 = 64 + tr;
                    if (tr1 < tiln) {
                        int tok2 = btoke[t0 + tr1];
                        float w = bwe[t0 + tr1];
                        float* dst = accb + (size_t)tok2 * DIM;
                        #pragma unroll
                        for (int nt = 0; nt < 8; nt++) {
                            int d = dq * 128 + nt * 16 + lm;
                            atomicAdd(dst + d, w * (yacc1[nt][r] + b2s[nt]));
                        }
                    }
                }
            }
        }
        __syncthreads();   // protect Hs/Ws before (rare) next pass
    }
}

// ---------------- residual + LayerNorm ----------------
__global__ void ln_kernel(const float* __restrict__ x,
                          const float* __restrict__ accb,
                          const float* __restrict__ gamma,
                          const float* __restrict__ beta,
                          float* __restrict__ out) {
    const int t = blockIdx.x;
    const int tid = threadIdx.x;                  // 256
    __shared__ float red[8];
    const size_t base = (size_t)t * DIM;
    float v0 = x[base + tid] + accb[base + tid];
    float v1 = x[base + 256 + tid] + accb[base + 256 + tid];
    float s  = v0 + v1;
    float sq = v0 * v0 + v1 * v1;
    #pragma unroll
    for (int off = 32; off; off >>= 1) { s += __shfl_xor(s, off); sq += __shfl_xor(sq, off); }
    if ((tid & 63) == 0) { red[tid >> 6] = s; red[4 + (tid >> 6)] = sq; }
    __syncthreads();
    float S  = red[0] + red[1] + red[2] + red[3];
    float SQ = red[4] + red[5] + red[6] + red[7];
    float mu  = S * (1.f / DIM);
    float var = SQ * (1.f / DIM) - mu * mu;
    float inv = rsqrtf(var + LN_EPS);
    out[base + tid]       = (v0 - mu) * inv * gamma[tid]       + beta[tid];
    out[base + 256 + tid] = (v1 - mu) * inv * gamma[256 + tid] + beta[256 + tid];
}

extern "C" void kernel_launch(void* const* d_in, const int* in_sizes, int n_in,
                              void* d_out, int out_size, void* d_ws, size_t ws_size,
                              hipStream_t stream) {
    const float* x     = (const float*)d_in[0];
    const float* Wg    = (const float*)d_in[1];
    const float* bg    = (const float*)d_in[2];
    const float* W1    = (const float*)d_in[3];
    const float* b1    = (const float*)d_in[4];
    const float* W2    = (const float*)d_in[5];
    const float* b2    = (const float*)d_in[6];
    const float* gamma = (const float*)d_in[7];
    const float* beta  = (const float*)d_in[8];

    char* ws = (char*)d_ws;
    int*   counts = (int*)ws;                                  // 256 B
    int*   btok   = (int*)(ws + 4096);                          // 512 KB
    float* bwv    = (float*)(ws + 4096 + 524288);               // 512 KB
    float* accb   = (float*)(ws + 4096 + 2 * 524288);           // 4 MB

    init_kernel<<<1024, 256, 0, stream>>>((float4*)accb, counts);
    gate_kernel<<<NTOK, 64, 0, stream>>>(x, Wg, bg, counts, btok, bwv);
    ffn_kernel<<<NEXP * NSLICE, 256, 0, stream>>>(x, W1, b1, W2, b2,
                                                  counts, btok, bwv, accb);
    ln_kernel<<<NTOK, 256, 0, stream>>>(x, accb, gamma, beta, (float*)d_out);
}